// Round 5
// baseline (254.534 us; speedup 1.0000x reference)
//
#include <hip/hip_runtime.h>

// NetVLAD fp32, N=64 HW=1024 D=512 K=64. bf16 MFMA.
// R10: occupancy fix for the fused kernel. 64-px slabs -> xbT 64KB + ab 8KB
// = 72KB LDS -> 2 blocks/CU (was 144KB -> 1 block/CU -> 1 wave/SIMD, fully
// latency-exposed). Pass A role-split: waves 0,1 = register GEMM1 + softmax
// (proven R7 path, no scatter on its critical path); waves 2,3 re-load the
// same x lines (L1/L2-hot) and do the whole bf16 x^T scatter into LDS.
// All 4 waves run GEMM2 from LDS. Grid 512 = 64n x 8 chunks (2 slabs each).
//   kprep:  W[512][64] -> wt[64 k][512 d] bf16; zero a_sum/ssq.
//   kfused: x@W+b -> softmax -> ab; V += x^T@a from LDS; 8 partials/image.
//   kpost:  out = sum_c vpart + a_sum*C; atomic ssq.
//   kscale: intra-norm (per n,k over d) x global L2 (per n), in place.

#define EPSF 1e-12f

typedef short bf16x8 __attribute__((ext_vector_type(8)));
typedef float f32x16 __attribute__((ext_vector_type(16)));

__device__ inline unsigned short f2bf_rne(float f) {
  union { float f; unsigned u; } v; v.f = f;
  unsigned u = v.u;
  unsigned r = u + 0x7fffu + ((u >> 16) & 1u);
  return (unsigned short)(r >> 16);
}
__device__ inline unsigned pk2(float a, float b) {
#if __has_builtin(__builtin_amdgcn_cvt_pk_bf16_f32)
  auto r = __builtin_amdgcn_cvt_pk_bf16_f32(a, b);
  return __builtin_bit_cast(unsigned, r);
#else
  return (unsigned)f2bf_rne(a) | ((unsigned)f2bf_rne(b) << 16);
#endif
}

// ---------------- K0: W transpose (blocks 0-7) + zero stats (block 8) ------
__global__ __launch_bounds__(256) void kprep(
    const float* __restrict__ Wm, unsigned short* __restrict__ wt,
    float* __restrict__ stats /* a_sum(4096) + ssq(4096) */) {
  const int t = threadIdx.x, bx = blockIdx.x;
  if (bx == 8) {
    float4 z = {0.f, 0.f, 0.f, 0.f};
#pragma unroll
    for (int r = 0; r < 8; ++r)
      *(float4*)&stats[(size_t)(r * 256 + t) * 4] = z;
    return;
  }
  __shared__ float tile[64][65];
  {
    int col = (t & 15) * 4, rbase = t >> 4;
#pragma unroll
    for (int r = 0; r < 4; ++r) {
      int row = rbase + 16 * r;
      *(float4*)&tile[row][col] =
          *(const float4*)&Wm[(size_t)(bx * 64 + row) * 64 + col];
    }
  }
  __syncthreads();
  int k = t >> 2, seg = (t & 3) * 16;
  size_t o = (size_t)k * 512 + bx * 64 + seg;
#pragma unroll
  for (int j = 0; j < 16; j += 2)
    *(unsigned*)&wt[o + j] = pk2(tile[seg + j][k], tile[seg + j + 1][k]);
}

// ---------------- fused assign + vlad --------------------------------------
// grid 512 = (n=bid>>3, chunk c=bid&7 of 128 px). 4 waves x 64 lanes.
// LDS: xbT[512 d][64 px] bf16 (64KB) + ab[64 k][64 px] (8KB) = 72KB,
// 2 blocks/CU. Two 64-px slabs per chunk. Both tiles XOR-swizzled by row&7.
__global__ __launch_bounds__(256, 2) void kfused(
    const float* __restrict__ x, const unsigned short* __restrict__ wt,
    const float* __restrict__ b, float* __restrict__ vpart,
    float* __restrict__ a_sum) {
  __shared__ unsigned short xbT[512 * 64];   // [d][px ^ ((d&7)<<3)]
  __shared__ unsigned short ab[64 * 64];     // [k][px ^ ((k&7)<<3)]
  const int t = threadIdx.x;
  const int w = t >> 6, lane = t & 63, l31 = lane & 31, h = lane >> 5;
  const int bid = blockIdx.x;
  const int n = bid >> 3, c = bid & 7;
  const unsigned short* w0 = wt + (size_t)l31 * 512;
  const unsigned short* w1 = wt + (size_t)(32 + l31) * 512;
  const float bias0 = b[l31], bias1 = b[32 + l31];
  const bool gw = (w < 2);                   // waves 0,1: GEMM1+softmax
  const int pxl = (w & 1) * 32 + l31;        // lane's px within slab (0..63)

  f32x16 accv[8];                            // [dt 0..3][kt 0..1]
#pragma unroll
  for (int i = 0; i < 8; ++i)
#pragma unroll
    for (int j = 0; j < 16; ++j) accv[i][j] = 0.f;

  float asum0 = 0.f, asum1 = 0.f;

  for (int s = 0; s < 2; ++s) {
    const int pxb = c * 128 + s * 64;
    const float* rowp = x + ((size_t)n * 1024 + pxb + pxl) * 512;
    if (gw) {
      // ---- waves 0,1: register GEMM1 (32 px x 64 k) ----
      f32x16 s0, s1;
#pragma unroll
      for (int i = 0; i < 16; ++i) { s0[i] = 0.f; s1[i] = 0.f; }
#pragma unroll 8
      for (int st = 0; st < 32; ++st) {
        const int kd = st * 16 + h * 8;
        float4 xa = *(const float4*)&rowp[kd];
        float4 xb = *(const float4*)&rowp[kd + 4];
        union { unsigned u[4]; bf16x8 v; } ax;
        ax.u[0] = pk2(xa.x, xa.y);
        ax.u[1] = pk2(xa.z, xa.w);
        ax.u[2] = pk2(xb.x, xb.y);
        ax.u[3] = pk2(xb.z, xb.w);
        bf16x8 b0 = *(const bf16x8*)&w0[kd];
        bf16x8 b1 = *(const bf16x8*)&w1[kd];
        s0 = __builtin_amdgcn_mfma_f32_32x32x16_bf16(ax.v, b0, s0, 0, 0, 0);
        s1 = __builtin_amdgcn_mfma_f32_32x32x16_bf16(ax.v, b1, s1, 0, 0, 0);
      }
      // ---- softmax over k -> ab (swizzled), a_sum partials ----
      float a0[16], a1[16];
      float sum0 = 0.f, sum1 = 0.f;
#pragma unroll
      for (int r = 0; r < 16; ++r) {
        float v0 = s0[r] + bias0, v1 = s1[r] + bias1;
        float m = fmaxf(v0, v1);
#pragma unroll
        for (int msk = 1; msk < 32; msk <<= 1)
          m = fmaxf(m, __shfl_xor(m, msk, 64));
        float e0 = __expf(v0 - m), e1 = __expf(v1 - m);
        float S = e0 + e1;
#pragma unroll
        for (int msk = 1; msk < 32; msk <<= 1) S += __shfl_xor(S, msk, 64);
        float inv = 1.0f / S;
        a0[r] = e0 * inv; a1[r] = e1 * inv;
        sum0 += a0[r]; sum1 += a1[r];
      }
      asum0 += sum0; asum1 += sum1;
#pragma unroll
      for (int g = 0; g < 4; ++g) {
        const int cb = (w & 1) * 32 + 8 * g + 4 * h;  // 4 consecutive px
        uint2 uu;
        uu.x = pk2(a0[4 * g + 0], a0[4 * g + 1]);
        uu.y = pk2(a0[4 * g + 2], a0[4 * g + 3]);
        *(uint2*)&ab[l31 * 64 + (cb ^ ((l31 & 7) << 3))] = uu;
        uu.x = pk2(a1[4 * g + 0], a1[4 * g + 1]);
        uu.y = pk2(a1[4 * g + 2], a1[4 * g + 3]);
        *(uint2*)&ab[(32 + l31) * 64 + (cb ^ ((l31 & 7) << 3))] = uu;
      }
    } else {
      // ---- waves 2,3: x^T bf16 scatter (same lines -> L1/L2 hits) ----
#pragma unroll 8
      for (int st = 0; st < 32; ++st) {
        const int kd = st * 16 + h * 8;
        float4 xa = *(const float4*)&rowp[kd];
        float4 xb = *(const float4*)&rowp[kd + 4];
        unsigned u[4];
        u[0] = pk2(xa.x, xa.y);
        u[1] = pk2(xa.z, xa.w);
        u[2] = pk2(xb.x, xb.y);
        u[3] = pk2(xb.z, xb.w);
#pragma unroll
        for (int j2 = 0; j2 < 4; ++j2) {
          const int da = kd + 2 * j2, db = da + 1;
          xbT[da * 64 + (pxl ^ ((da & 7) << 3))] =
              (unsigned short)(u[j2] & 0xffffu);
          xbT[db * 64 + (pxl ^ ((db & 7) << 3))] =
              (unsigned short)(u[j2] >> 16);
        }
      }
    }
    __syncthreads();
    // ---- GEMM2: all 4 waves, V[dw..dw+127][0..63] += x^T @ a ----
    const int dw = w * 128;
#pragma unroll
    for (int s8 = 0; s8 < 4; ++s8) {
      const int px0 = s8 * 16 + 8 * h;
      bf16x8 bb0 = *(const bf16x8*)&ab[l31 * 64 + (px0 ^ ((l31 & 7) << 3))];
      bf16x8 bb1 =
          *(const bf16x8*)&ab[(32 + l31) * 64 + (px0 ^ ((l31 & 7) << 3))];
#pragma unroll
      for (int dt = 0; dt < 4; ++dt) {
        const int dr = dw + dt * 32 + l31;
        bf16x8 aa = *(const bf16x8*)&xbT[dr * 64 + (px0 ^ ((dr & 7) << 3))];
        accv[dt * 2 + 0] =
            __builtin_amdgcn_mfma_f32_32x32x16_bf16(aa, bb0, accv[dt * 2 + 0], 0, 0, 0);
        accv[dt * 2 + 1] =
            __builtin_amdgcn_mfma_f32_32x32x16_bf16(aa, bb1, accv[dt * 2 + 1], 0, 0, 0);
      }
    }
    __syncthreads();   // before next slab overwrites xbT/ab
  }
  // a_sum (waves 0,1 cover px 0..63 across both slabs)
  if (gw) {
    asum0 += __shfl_xor(asum0, 32, 64);
    asum1 += __shfl_xor(asum1, 32, 64);
    if (lane < 32) {
      atomicAdd(&a_sum[n * 64 + l31], asum0);
      atomicAdd(&a_sum[n * 64 + 32 + l31], asum1);
    }
  }
  // epilogue: plain-write this chunk's partial V [512][64]
  float* vp = vpart + (size_t)c * 2097152 + (size_t)n * 32768;
#pragma unroll
  for (int dt = 0; dt < 4; ++dt) {
#pragma unroll
    for (int kt = 0; kt < 2; ++kt) {
      const f32x16 a = accv[dt * 2 + kt];
      const int kcol = kt * 32 + l31;
#pragma unroll
      for (int r = 0; r < 16; ++r) {
        const int drow = w * 128 + dt * 32 + (r & 3) + 8 * (r >> 2) + 4 * h;
        vp[drow * 64 + kcol] = a[r];
      }
    }
  }
}

// ---------------- kpost: out = sum_c vpart + a_sum*C; atomic ssq -----------
__global__ __launch_bounds__(256) void kpost(
    const float* __restrict__ vpart, const float* __restrict__ a_sum,
    const float* __restrict__ C, float* __restrict__ out,
    float* __restrict__ ssq) {
  const int bid = blockIdx.x;               // 512: n fast for locality
  const int n = bid & 63, d0 = (bid >> 6) * 64;
  const int t = threadIdx.x, k = t & 63, dr = t >> 6;
  const float as = a_sum[n * 64 + k];
  const size_t nb = (size_t)n * 32768;
  float sq = 0.f;
#pragma unroll
  for (int r = 0; r < 16; ++r) {
    const int d = d0 + dr * 16 + r;
    const size_t idx = nb + (size_t)d * 64 + k;
    float o = as * C[(size_t)d * 64 + k];
#pragma unroll
    for (int cc = 0; cc < 8; ++cc) o += vpart[idx + (size_t)cc * 2097152];
    out[idx] = o;
    sq += o * o;
  }
  atomicAdd(&ssq[n * 64 + k], sq);
}

// ---------------- kscale: normalize in place -------------------------------
__global__ __launch_bounds__(256) void kscale(
    float* __restrict__ out, const float* __restrict__ ssq) {
  const int n = blockIdx.y, slice = blockIdx.x;
  const int t = threadIdx.x, k = t & 63, rg = t >> 6;
  __shared__ float sk[64];
  __shared__ float tot;
  if (t < 64) {
    float cc = ssq[n * 64 + t];
    sk[t] = rsqrtf(cc + EPSF);
    float contrib = cc / (cc + EPSF);
#pragma unroll
    for (int m = 32; m; m >>= 1) contrib += __shfl_xor(contrib, m, 64);
    if (t == 0) tot = rsqrtf(contrib + EPSF);
  }
  __syncthreads();
  const float scale = sk[k] * tot;
  float* vb = out + (size_t)n * 32768 + (size_t)slice * 4096;
#pragma unroll
  for (int r = rg; r < 64; r += 4) vb[r * 64 + k] *= scale;
}

extern "C" void kernel_launch(void* const* d_in, const int* in_sizes, int n_in,
                              void* d_out, int out_size, void* d_ws, size_t ws_size,
                              hipStream_t stream) {
  const float* x  = (const float*)d_in[0];   // [64,32,32,512]
  const float* Wm = (const float*)d_in[1];   // [512,64]
  const float* b  = (const float*)d_in[2];   // [64]
  const float* C  = (const float*)d_in[3];   // [512,64]
  float* out = (float*)d_out;                // [64, 32768]

  float* vpart = (float*)d_ws;                         // 64 MiB: 8 x [64][512][64]
  unsigned short* wt = (unsigned short*)(vpart + (size_t)8 * 2097152);  // 64 KiB
  float* stats = (float*)(wt + (size_t)64 * 512);      // a_sum 4096 + ssq 4096
  float* a_sum = stats;
  float* ssq   = stats + 4096;

  kprep<<<dim3(9), dim3(256), 0, stream>>>(Wm, wt, stats);
  kfused<<<dim3(512), dim3(256), 0, stream>>>(x, wt, b, vpart, a_sum);
  kpost<<<dim3(512), dim3(256), 0, stream>>>(vpart, a_sum, C, out, ssq);
  kscale<<<dim3(8, 64), dim3(256), 0, stream>>>(out, ssq);
}

// Round 6
// 230.103 us; speedup vs baseline: 1.1062x; 1.1062x over previous
//
#include <hip/hip_runtime.h>

// NetVLAD fp32, N=64 HW=1024 D=512 K=64. bf16 MFMA.
// R11: R9 structure + SWAPPED GEMM1 (mfma(W,x) -> D[k][px], lane=px) so the
// softmax k-reduction is lane-local: 31 VALU + 1 shfl_xor(32) instead of 160
// chained shuffles per wave (R10 counters: everything idle -> serial-chain
// bound). a_sum via ILP-32 butterfly (5 wide rounds, f32-exact). Uniform
// waves, x read once, inline x^T scatter. 256 blocks, 144KB LDS.
//   kprep:  W[512][64] -> wt[64 k][512 d] bf16; zero a_sum/ssq.
//   kfused: s=x@W+b (swapped), softmax lane-local -> ab; V += x^T@a; partials.
//   kpost:  out = sum_c vpart + a_sum*C; atomic ssq.
//   kscale: intra-norm (per n,k over d) x global L2 (per n), in place.

#define EPSF 1e-12f

typedef short bf16x8 __attribute__((ext_vector_type(8)));
typedef float f32x16 __attribute__((ext_vector_type(16)));

__device__ inline unsigned short f2bf_rne(float f) {
  union { float f; unsigned u; } v; v.f = f;
  unsigned u = v.u;
  unsigned r = u + 0x7fffu + ((u >> 16) & 1u);
  return (unsigned short)(r >> 16);
}
__device__ inline unsigned pk2(float a, float b) {
#if __has_builtin(__builtin_amdgcn_cvt_pk_bf16_f32)
  auto r = __builtin_amdgcn_cvt_pk_bf16_f32(a, b);
  return __builtin_bit_cast(unsigned, r);
#else
  return (unsigned)f2bf_rne(a) | ((unsigned)f2bf_rne(b) << 16);
#endif
}

// ---------------- K0: W transpose (blocks 0-7) + zero stats (block 8) ------
__global__ __launch_bounds__(256) void kprep(
    const float* __restrict__ Wm, unsigned short* __restrict__ wt,
    float* __restrict__ stats /* a_sum(4096) + ssq(4096) */) {
  const int t = threadIdx.x, bx = blockIdx.x;
  if (bx == 8) {
    float4 z = {0.f, 0.f, 0.f, 0.f};
#pragma unroll
    for (int r = 0; r < 8; ++r)
      *(float4*)&stats[(size_t)(r * 256 + t) * 4] = z;
    return;
  }
  __shared__ float tile[64][65];
  {
    int col = (t & 15) * 4, rbase = t >> 4;
#pragma unroll
    for (int r = 0; r < 4; ++r) {
      int row = rbase + 16 * r;
      *(float4*)&tile[row][col] =
          *(const float4*)&Wm[(size_t)(bx * 64 + row) * 64 + col];
    }
  }
  __syncthreads();
  int k = t >> 2, seg = (t & 3) * 16;
  size_t o = (size_t)k * 512 + bx * 64 + seg;
#pragma unroll
  for (int j = 0; j < 16; j += 2)
    *(unsigned*)&wt[o + j] = pk2(tile[seg + j][k], tile[seg + j + 1][k]);
}

// ---------------- fused assign + vlad --------------------------------------
// grid 256 = (n=bid>>2, chunk c=bid&3 of 256 px). 4 waves x 64 lanes.
// LDS: xbT[512 d][128 px] bf16 (128KB, XOR-swizzled) + ab[64 k][128 px]
// (16KB) = 144KB, 1 block/CU. Two 128-px slabs per chunk.
__global__ __launch_bounds__(256, 1) void kfused(
    const float* __restrict__ x, const unsigned short* __restrict__ wt,
    const float* __restrict__ b, float* __restrict__ vpart,
    float* __restrict__ a_sum) {
  __shared__ unsigned short xbT[512 * 128];  // [d][px ^ ((d&15)<<3)]
  __shared__ unsigned short ab[64 * 128];    // [k][px ^ ((k&15)<<3)]
  const int t = threadIdx.x;
  const int w = t >> 6, lane = t & 63, l31 = lane & 31, h = lane >> 5;
  const int bid = blockIdx.x;
  const int n = bid >> 2, c = bid & 3;
  const unsigned short* w0 = wt + (size_t)l31 * 512;
  const unsigned short* w1 = wt + (size_t)(32 + l31) * 512;
  const int colpx = w * 32 + l31;            // this lane's px column (0..127)

  // per-reg bias: reg r of acc D[k][px] holds k = (r&3)+8*(r>>2)+4h
  float bias0[16], bias1[16];
#pragma unroll
  for (int r = 0; r < 16; ++r) {
    const int k0 = (r & 3) + 8 * (r >> 2) + 4 * h;
    bias0[r] = b[k0];
    bias1[r] = b[k0 + 32];
  }

  f32x16 accv[8];                            // [dt 0..3][kt 0..1]
#pragma unroll
  for (int i = 0; i < 8; ++i)
#pragma unroll
    for (int j = 0; j < 16; ++j) accv[i][j] = 0.f;

  float sa0[16], sa1[16];                    // per-k a-sums over this lane's px
#pragma unroll
  for (int r = 0; r < 16; ++r) { sa0[r] = 0.f; sa1[r] = 0.f; }

  for (int s = 0; s < 2; ++s) {
    const int pxb = c * 256 + s * 128;
    // ---- pass A: swapped GEMM1 + inline x^T bf16 scatter into LDS ----
    const float* rowp = x + ((size_t)n * 1024 + pxb + colpx) * 512;
    f32x16 s0, s1;
#pragma unroll
    for (int i = 0; i < 16; ++i) { s0[i] = 0.f; s1[i] = 0.f; }
#pragma unroll 8
    for (int st = 0; st < 32; ++st) {
      const int kd = st * 16 + h * 8;
      float4 xa = *(const float4*)&rowp[kd];
      float4 xb = *(const float4*)&rowp[kd + 4];
      union { unsigned u[4]; bf16x8 v; } ax;
      ax.u[0] = pk2(xa.x, xa.y);
      ax.u[1] = pk2(xa.z, xa.w);
      ax.u[2] = pk2(xb.x, xb.y);
      ax.u[3] = pk2(xb.z, xb.w);
      bf16x8 b0 = *(const bf16x8*)&w0[kd];
      bf16x8 b1 = *(const bf16x8*)&w1[kd];
      // SWAPPED: A = W (lane=k-row), B = x (lane=px-col) -> D[k][px], lane=px
      s0 = __builtin_amdgcn_mfma_f32_32x32x16_bf16(b0, ax.v, s0, 0, 0, 0);
      s1 = __builtin_amdgcn_mfma_f32_32x32x16_bf16(b1, ax.v, s1, 0, 0, 0);
#pragma unroll
      for (int j2 = 0; j2 < 4; ++j2) {
        const int da = kd + 2 * j2, db = da + 1;
        xbT[da * 128 + (colpx ^ ((da & 15) << 3))] =
            (unsigned short)(ax.u[j2] & 0xffffu);
        xbT[db * 128 + (colpx ^ ((db & 15) << 3))] =
            (unsigned short)(ax.u[j2] >> 16);
      }
    }
    // ---- lane-local softmax over k (32 regs here + 32 in partner lane) ----
    float v0[16], v1[16];
    float m = -3.402823466e+38f;
#pragma unroll
    for (int r = 0; r < 16; ++r) {
      v0[r] = s0[r] + bias0[r];
      v1[r] = s1[r] + bias1[r];
      m = fmaxf(m, fmaxf(v0[r], v1[r]));
    }
    m = fmaxf(m, __shfl_xor(m, 32, 64));     // combine h-halves (same px)
    float e0[16], e1[16];
    float S = 0.f;
#pragma unroll
    for (int r = 0; r < 16; ++r) {
      e0[r] = __expf(v0[r] - m);
      e1[r] = __expf(v1[r] - m);
      S += e0[r] + e1[r];
    }
    S += __shfl_xor(S, 32, 64);
    const float inv = 1.0f / S;
    // a -> ab LDS (bf16, RNE) + f32 a-sum accumulation
#pragma unroll
    for (int r = 0; r < 16; ++r) {
      const float a0 = e0[r] * inv, a1 = e1[r] * inv;
      sa0[r] += a0; sa1[r] += a1;
      const int k0 = (r & 3) + 8 * (r >> 2) + 4 * h, k1 = k0 + 32;
      ab[k0 * 128 + (colpx ^ ((k0 & 15) << 3))] = f2bf_rne(a0);
      ab[k1 * 128 + (colpx ^ ((k1 & 15) << 3))] = f2bf_rne(a1);
    }
    __syncthreads();
    // ---- pass B: GEMM2 V[d][k] += x^T @ a from LDS ----
    const int dw = w * 128;
#pragma unroll
    for (int s8 = 0; s8 < 8; ++s8) {
      const int px0 = s8 * 16 + 8 * h;
      bf16x8 bb0 = *(const bf16x8*)&ab[l31 * 128 + (px0 ^ ((l31 & 15) << 3))];
      bf16x8 bb1 =
          *(const bf16x8*)&ab[(32 + l31) * 128 + (px0 ^ ((l31 & 15) << 3))];
#pragma unroll
      for (int dt = 0; dt < 4; ++dt) {
        const int dr = dw + dt * 32 + l31;
        bf16x8 aa = *(const bf16x8*)&xbT[dr * 128 + (px0 ^ ((dr & 15) << 3))];
        accv[dt * 2 + 0] =
            __builtin_amdgcn_mfma_f32_32x32x16_bf16(aa, bb0, accv[dt * 2 + 0], 0, 0, 0);
        accv[dt * 2 + 1] =
            __builtin_amdgcn_mfma_f32_32x32x16_bf16(aa, bb1, accv[dt * 2 + 1], 0, 0, 0);
      }
    }
    __syncthreads();   // before next slab overwrites xbT/ab
  }
  // ---- a_sum: ILP-32 butterfly over the 32 px-lanes of each h-half ----
#pragma unroll
  for (int msk = 1; msk < 32; msk <<= 1) {
#pragma unroll
    for (int r = 0; r < 16; ++r) {
      sa0[r] += __shfl_xor(sa0[r], msk, 64);
      sa1[r] += __shfl_xor(sa1[r], msk, 64);
    }
  }
  if (l31 < 16) {
    const int r = l31;
    const int k0 = (r & 3) + 8 * (r >> 2) + 4 * h;
    atomicAdd(&a_sum[n * 64 + k0], sa0[r]);
    atomicAdd(&a_sum[n * 64 + k0 + 32], sa1[r]);
  }
  // epilogue: plain-write this chunk's partial V [512][64]
  float* vp = vpart + (size_t)c * 2097152 + (size_t)n * 32768;
#pragma unroll
  for (int dt = 0; dt < 4; ++dt) {
#pragma unroll
    for (int kt = 0; kt < 2; ++kt) {
      const f32x16 a = accv[dt * 2 + kt];
      const int kcol = kt * 32 + l31;
#pragma unroll
      for (int r = 0; r < 16; ++r) {
        const int drow = w * 128 + dt * 32 + (r & 3) + 8 * (r >> 2) + 4 * h;
        vp[drow * 64 + kcol] = a[r];
      }
    }
  }
}

// ---------------- kpost: out = sum_c vpart + a_sum*C; atomic ssq -----------
__global__ __launch_bounds__(256) void kpost(
    const float* __restrict__ vpart, const float* __restrict__ a_sum,
    const float* __restrict__ C, float* __restrict__ out,
    float* __restrict__ ssq) {
  const int bid = blockIdx.x;               // 512: n fast for locality
  const int n = bid & 63, d0 = (bid >> 6) * 64;
  const int t = threadIdx.x, k = t & 63, dr = t >> 6;
  const float as = a_sum[n * 64 + k];
  const size_t nb = (size_t)n * 32768;
  float sq = 0.f;
#pragma unroll
  for (int r = 0; r < 16; ++r) {
    const int d = d0 + dr * 16 + r;
    const size_t idx = nb + (size_t)d * 64 + k;
    float o = vpart[idx] + vpart[idx + 2097152] + vpart[idx + 4194304] +
              vpart[idx + 6291456] + as * C[(size_t)d * 64 + k];
    out[idx] = o;
    sq += o * o;
  }
  atomicAdd(&ssq[n * 64 + k], sq);
}

// ---------------- kscale: normalize in place -------------------------------
__global__ __launch_bounds__(256) void kscale(
    float* __restrict__ out, const float* __restrict__ ssq) {
  const int n = blockIdx.y, slice = blockIdx.x;
  const int t = threadIdx.x, k = t & 63, rg = t >> 6;
  __shared__ float sk[64];
  __shared__ float tot;
  if (t < 64) {
    float cc = ssq[n * 64 + t];
    sk[t] = rsqrtf(cc + EPSF);
    float contrib = cc / (cc + EPSF);
#pragma unroll
    for (int m = 32; m; m >>= 1) contrib += __shfl_xor(contrib, m, 64);
    if (t == 0) tot = rsqrtf(contrib + EPSF);
  }
  __syncthreads();
  const float scale = sk[k] * tot;
  float* vb = out + (size_t)n * 32768 + (size_t)slice * 4096;
#pragma unroll
  for (int r = rg; r < 64; r += 4) vb[r * 64 + k] *= scale;
}

extern "C" void kernel_launch(void* const* d_in, const int* in_sizes, int n_in,
                              void* d_out, int out_size, void* d_ws, size_t ws_size,
                              hipStream_t stream) {
  const float* x  = (const float*)d_in[0];   // [64,32,32,512]
  const float* Wm = (const float*)d_in[1];   // [512,64]
  const float* b  = (const float*)d_in[2];   // [64]
  const float* C  = (const float*)d_in[3];   // [512,64]
  float* out = (float*)d_out;                // [64, 32768]

  float* vpart = (float*)d_ws;                         // 32 MiB: 4 x [64][512][64]
  unsigned short* wt = (unsigned short*)(vpart + (size_t)4 * 2097152);  // 64 KiB
  float* stats = (float*)(wt + (size_t)64 * 512);      // a_sum 4096 + ssq 4096
  float* a_sum = stats;
  float* ssq   = stats + 4096;

  kprep<<<dim3(9), dim3(256), 0, stream>>>(Wm, wt, stats);
  kfused<<<dim3(256), dim3(256), 0, stream>>>(x, wt, b, vpart, a_sum);
  kpost<<<dim3(512), dim3(256), 0, stream>>>(vpart, a_sum, C, out, ssq);
  kscale<<<dim3(8, 64), dim3(256), 0, stream>>>(out, ssq);
}